// Round 4
// baseline (6062.232 us; speedup 1.0000x reference)
//
#include <hip/hip_runtime.h>
#include <hip/hip_fp16.h>

#define S 31
#define D 14
#define H 50
#define NB 16384
#define NITER 48
#define LAMR 1e-4f
#define SC 2.8853900817779268f   // 2*log2(e): folded into Wh,Wx,Wo,bh+bx,bo

// ws float-index layout
#define WS_D2   0      // 48: global sum ||F-X||^2 per iter
#define WS_F2   64     // 48: global sum ||F||^2 per iter
#define WS_WHP  128    // 50x16 fp32 Wh*SC (padded)
#define WS_BHX  928    // 64: (bh+bx)*SC fp32
#define WS_BO   992    // 16: bo*SC fp32
#define WS_WX2  1024   // 50x8 f16x2: Wx*SC rows packed (d pairs)
#define WS_WO2  1424   // 14x28 f16x2: Wo*SC rows packed (h pairs, padded to 28)
#define WS_WF2  1824   // 32x8 f16x2: Wf per-s slices (row 31 = 0), UNSCALED
#define WS_OUTK 4096   // 48*NB floats

typedef _Float16 f16x2 __attribute__((ext_vector_type(2)));

#if defined(__has_builtin) && __has_builtin(__builtin_amdgcn_rcpf)
#define FRCP(x) __builtin_amdgcn_rcpf(x)
#else
#define FRCP(x) (1.0f/(x))
#endif

#define FDOT2(a,b,c) __builtin_amdgcn_fdot2((a),(b),(c),false)

__device__ __forceinline__ f16x2 pkrtz(float a, float b){
  auto r = __builtin_amdgcn_cvt_pkrtz(a, b);
  return __builtin_bit_cast(f16x2, r);
}
#define PKRTZ(a,b) pkrtz((a),(b))

// scaled tanh: input u = 2*log2(e)*x  ->  tanh(x) = 1 - 2/(2^u + 1)
__device__ __forceinline__ float tsc(float u){
  float e = __builtin_exp2f(u);
  return 1.f - 2.f * FRCP(e + 1.f);
}

// triangular index, i<=j, 6x6
#define AIJ(i,j) ((i)*6 - ((i)*((i)+1))/2 + (j))

__device__ __forceinline__ float half_red(float v){
  v += __shfl_xor(v, 1);
  v += __shfl_xor(v, 2);
  v += __shfl_xor(v, 4);
  v += __shfl_xor(v, 8);
  v += __shfl_xor(v, 16);
  return v;   // sum over 32-lane half
}

__global__ void prep_kernel(const float* __restrict__ Wh, const float* __restrict__ bh,
                            const float* __restrict__ Wx, const float* __restrict__ bx,
                            const float* __restrict__ Wo, const float* __restrict__ bo,
                            const float* __restrict__ Wf, float* __restrict__ ws){
  int t = threadIdx.x;                       // 1 block x 256
  for (int i=t;i<128;i+=256) ws[i]=0.f;      // zero norm accumulators
  for (int i=t;i<800;i+=256){
    int h=i>>4, d=i&15;
    ws[WS_WHP+i] = (d<D)? Wh[h*D+d]*SC : 0.f;
  }
  for (int i=t;i<64;i+=256) ws[WS_BHX+i] = (i<H)? (bh[i]+bx[i])*SC : 0.f;
  for (int i=t;i<16;i+=256) ws[WS_BO+i]  = (i<D)? bo[i]*SC : 0.f;
  __half2* wx2 = (__half2*)(ws + WS_WX2);
  for (int i=t;i<400;i+=256){
    int h=i>>3, dd=i&7, d0=2*dd, d1=2*dd+1;
    float a=(d0<D)?Wx[h*D+d0]*SC:0.f, b=(d1<D)?Wx[h*D+d1]*SC:0.f;
    wx2[i] = __floats2half2_rn(a,b);
  }
  __half2* wo2 = (__half2*)(ws + WS_WO2);
  for (int i=t;i<392;i+=256){
    int d=i/28, hh=i-28*d;
    float a=(hh<25)?Wo[d*H+2*hh]*SC:0.f, b=(hh<25)?Wo[d*H+2*hh+1]*SC:0.f;
    wo2[i] = __floats2half2_rn(a,b);
  }
  __half2* wf2 = (__half2*)(ws + WS_WF2);
  for (int i=t;i<256;i+=256){
    int s=i>>3, dd=i&7, d0=2*dd, d1=2*dd+1;
    float a=(s<S && d0<D)?Wf[s*D+d0]:0.f, b=(s<S && d1<D)?Wf[s*D+d1]:0.f;
    wf2[i] = __floats2half2_rn(a,b);
  }
}

// f-eval from LDS weights: fvh = tanh( Wo @ tanh(hx + Wx @ xvh) + bo )
#define FEVAL() do{ \
  f16x2 thh[25]; \
  _Pragma("unroll") \
  for (int hh_=0; hh_<25; ++hh_){ \
    f16x2 hx2_ = hxs[hh_*256 + tid]; \
    float a0_ = (float)hx2_.x, b0_ = (float)hx2_.y; \
    _Pragma("unroll") for (int q_=0;q_<7;++q_){ \
      a0_ = FDOT2(xvh[q_], wxs[(2*hh_)*8+q_],   a0_); \
      b0_ = FDOT2(xvh[q_], wxs[(2*hh_+1)*8+q_], b0_); } \
    thh[hh_] = PKRTZ(tsc(a0_), tsc(b0_)); \
  } \
  _Pragma("unroll") \
  for (int dp_=0; dp_<7; ++dp_){ \
    float t0_ = bos[2*dp_], t1_ = bos[2*dp_+1]; \
    float t0b_ = 0.f, t1b_ = 0.f; \
    _Pragma("unroll") for (int hh_=0;hh_<25;hh_+=2){ \
      t0_ = FDOT2(thh[hh_], wos[(2*dp_)*28+hh_],   t0_); \
      t1_ = FDOT2(thh[hh_], wos[(2*dp_+1)*28+hh_], t1_); } \
    _Pragma("unroll") for (int hh_=1;hh_<25;hh_+=2){ \
      t0b_ = FDOT2(thh[hh_], wos[(2*dp_)*28+hh_],   t0b_); \
      t1b_ = FDOT2(thh[hh_], wos[(2*dp_+1)*28+hh_], t1b_); } \
    fvh[dp_] = PKRTZ(tsc(t0_+t0b_), tsc(t1_+t1b_)); \
  } \
}while(0)

// zero F (fvh) and G (xvh, aliased) on inactive lanes
#define ZERO_INACT() do{ \
  if (!act){ \
    _Pragma("unroll") for (int q_=0;q_<7;++q_){ fvh[q_]=zzv; xvh[q_]=zzv; } \
  } \
}while(0)

// push (F=fvh, G=xvh) as newest history entry (slot 5), update triangular GG
#define PUSH() do{ \
  float dnew_[5]; \
  _Pragma("unroll") for (int j_=0;j_<5;++j_){ \
    float acc_=0.f; \
    _Pragma("unroll") for (int q_=0;q_<7;++q_) acc_ = FDOT2(xvh[q_], Gh[(j_+1)*7+q_], acc_); \
    dnew_[j_] = half_red(acc_); } \
  float d2l=0.f, f2l=0.f; \
  _Pragma("unroll") for (int q_=0;q_<7;++q_){ \
    d2l = FDOT2(xvh[q_], xvh[q_], d2l); \
    f2l = FDOT2(fvh[q_], fvh[q_], f2l); } \
  d2r = half_red(d2l); f2r = half_red(f2l); \
  _Pragma("unroll") for (int j_=0;j_<5;++j_) \
    _Pragma("unroll") for (int q_=0;q_<7;++q_){ \
      Fh[j_*7+q_] = Fh[(j_+1)*7+q_]; Gh[j_*7+q_] = Gh[(j_+1)*7+q_]; } \
  _Pragma("unroll") for (int q_=0;q_<7;++q_){ Fh[35+q_]=fvh[q_]; Gh[35+q_]=xvh[q_]; } \
  _Pragma("unroll") for (int i_=0;i_<5;++i_) \
    _Pragma("unroll") for (int j_=i_;j_<5;++j_) GG[AIJ(i_,j_)] = GG[AIJ(i_+1,j_+1)]; \
  _Pragma("unroll") for (int j_=0;j_<5;++j_) GG[AIJ(j_,5)] = dnew_[j_]; \
  GG[AIJ(5,5)] = d2r; \
}while(0)

__global__ __launch_bounds__(256, 3)
void solver_kernel(const float* __restrict__ x,
                   const float* __restrict__ whp, const float* __restrict__ bhx,
                   const float* __restrict__ bopg,
                   const f16x2* __restrict__ wx2g, const f16x2* __restrict__ wo2g,
                   const f16x2* __restrict__ wf2g,
                   float* __restrict__ outk, float* __restrict__ d2p, float* __restrict__ f2p){
  const int tid  = threadIdx.x;
  const int lane = tid & 63;
  const int s    = tid & 31;
  const int elem = blockIdx.x*8 + (tid>>5);
  const bool act = (s < S);

  __shared__ f16x2 hxs[25*256];   // [hh][tid]: lane-consecutive -> conflict-free
  __shared__ f16x2 wxs[400];      // Wx*SC [50][8]
  __shared__ f16x2 wos[392];      // Wo*SC [14][28]
  __shared__ f16x2 wfs[256];      // Wf    [32][8]
  __shared__ float bos[16];       // bo*SC

  // stage weights to LDS
  for (int i=tid;i<400;i+=256) wxs[i]=wx2g[i];
  for (int i=tid;i<392;i+=256) wos[i]=wo2g[i];
  if (tid<256) wfs[tid]=wf2g[tid];
  if (tid<16)  bos[tid]=bopg[tid];

  { // prologue: hx[h] = SC*(x_s . Wh_h + bh_h + bx_h), fp32 math, fp16 store
    float xd[D];
#pragma unroll
    for (int d=0; d<D; ++d) xd[d]=0.f;
    if (act){
      const float* xr = x + ((size_t)elem*S + s)*D;
#pragma unroll
      for (int d=0; d<D; ++d) xd[d]=xr[d];
    }
#pragma unroll 1
    for (int hh=0; hh<25; ++hh){
      float a0 = bhx[2*hh], a1 = 0.f, b0 = bhx[2*hh+1], b1 = 0.f;
#pragma unroll
      for (int d=0; d<D; d+=2){
        a0 += xd[d]*whp[(2*hh)*16+d];   a1 += xd[d+1]*whp[(2*hh)*16+d+1];
        b0 += xd[d]*whp[(2*hh+1)*16+d]; b1 += xd[d+1]*whp[(2*hh+1)*16+d+1];
      }
      hxs[hh*256+tid] = PKRTZ(a0+a1, b0+b1);
    }
  }
  __syncthreads();

  const f16x2 zzv = {(_Float16)0.f, (_Float16)0.f};

  f16x2 Fh[42], Gh[42], xvh[7], fvh[7];
  float GG[21];
  float d2r, f2r;
#pragma unroll
  for (int i=0;i<42;++i){ Fh[i]=zzv; Gh[i]=zzv; }
#pragma unroll
  for (int i=0;i<21;++i) GG[i]=0.f;

  // init entry 0: X0=0, F0=f(0), G0=F0
#pragma unroll
  for (int q=0;q<7;++q) xvh[q]=zzv;
  FEVAL();
#pragma unroll
  for (int q=0;q<7;++q) xvh[q]=fvh[q]-xvh[q];
  ZERO_INACT();
  PUSH();
  // init entry 1: X1=F0, F1=f(F0)
#pragma unroll
  for (int q=0;q<7;++q) xvh[q]=Fh[35+q];
  FEVAL();
#pragma unroll
  for (int q=0;q<7;++q) xvh[q]=fvh[q]-xvh[q];
  ZERO_INACT();
  PUSH();

#pragma unroll 1
  for (int kk=2; kk<50; ++kk){
    float A_[21], yv[6];
    if (kk >= 6){
#pragma unroll
      for (int i=0;i<6;++i)
#pragma unroll
        for (int j=i;j<6;++j) A_[AIJ(i,j)] = GG[AIJ(i,j)] + ((i==j)?LAMR:0.f);
    } else {
      int lo = 6-kk;
#pragma unroll
      for (int i=0;i<6;++i)
#pragma unroll
        for (int j=i;j<6;++j){
          float v = GG[AIJ(i,j)] + ((i==j)?LAMR:0.f);
          A_[AIJ(i,j)] = (i>=lo)? v : ((i==j)?1e30f:0.f);
        }
    }
#pragma unroll
    for (int i=0;i<6;++i) yv[i]=1.f;
    // symmetric GE (no pivoting; SPD + big-diag pads); diag holds inverse
#pragma unroll
    for (int p=0;p<6;++p){
      float inv = FRCP(A_[AIJ(p,p)]);
      A_[AIJ(p,p)] = inv;
#pragma unroll
      for (int i=p+1;i<6;++i){
        float m = A_[AIJ(p,i)]*inv;
#pragma unroll
        for (int j=i;j<6;++j) A_[AIJ(i,j)] -= m*A_[AIJ(p,j)];
        yv[i] -= m*yv[p];
      }
    }
#pragma unroll
    for (int p=5;p>=0;--p){
      float acc=yv[p];
#pragma unroll
      for (int j=p+1;j<6;++j) acc -= A_[AIJ(p,j)]*yv[j];
      yv[p]=acc*A_[AIJ(p,p)];
    }
    float isum = FRCP(yv[0]+yv[1]+yv[2]+yv[3]+yv[4]+yv[5]);
    // Xk = sum_j alpha_j F_j  (fp16 packed)
#pragma unroll
    for (int q=0;q<7;++q) xvh[q]=zzv;
#pragma unroll
    for (int j=0;j<6;++j){
      _Float16 ah = (_Float16)(yv[j]*isum);
      f16x2 a2 = {ah, ah};
#pragma unroll
      for (int q=0;q<7;++q) xvh[q] += a2*Fh[j*7+q];
    }
    FEVAL();
#pragma unroll
    for (int q=0;q<7;++q) xvh[q]=fvh[q]-xvh[q];   // xvh now holds G
    ZERO_INACT();
    PUSH();
    // projection through Wf for this iterate
    float po=0.f;
    const f16x2* wfr = wfs + s*8;
#pragma unroll
    for (int q=0;q<7;++q) po = FDOT2(fvh[q], wfr[q], po);
    po = half_red(po);
    float d2w = d2r + __shfl_xor(d2r, 32);
    float f2w = f2r + __shfl_xor(f2r, 32);
    if (lane==0){ atomicAdd(&d2p[kk-2], d2w); atomicAdd(&f2p[kk-2], f2w); }
    if (s==0) outk[(size_t)(kk-2)*NB + elem] = po;
  }
}

__global__ void final_kernel(const float* __restrict__ d2p, const float* __restrict__ f2p,
                             const float* __restrict__ outk, const float* __restrict__ bf,
                             float* __restrict__ out){
  int b = blockIdx.x*blockDim.x + threadIdx.x;
  float best = 1e8f; int kst = 0;
  for (int k=0;k<NITER;++k){
    float rel = sqrtf(d2p[k]) / (1e-5f + sqrtf(f2p[k]));
    if (rel < best){ best = rel; kst = k; }
  }
  out[b] = outk[(size_t)kst*NB + b] + bf[0];
}

extern "C" void kernel_launch(void* const* d_in, const int* in_sizes, int n_in,
                              void* d_out, int out_size, void* d_ws, size_t ws_size,
                              hipStream_t stream){
  const float* x  = (const float*)d_in[0];
  const float* Wh = (const float*)d_in[1];
  const float* bh = (const float*)d_in[2];
  const float* Wx = (const float*)d_in[3];
  const float* bx = (const float*)d_in[4];
  const float* Wo = (const float*)d_in[5];
  const float* bo = (const float*)d_in[6];
  const float* Wf = (const float*)d_in[7];
  const float* bf = (const float*)d_in[8];
  float* ws  = (float*)d_ws;
  float* out = (float*)d_out;

  hipLaunchKernelGGL(prep_kernel, dim3(1), dim3(256), 0, stream, Wh,bh,Wx,bx,Wo,bo,Wf,ws);
  hipLaunchKernelGGL(solver_kernel, dim3(NB/8), dim3(256), 0, stream,
                     x, ws+WS_WHP, ws+WS_BHX, ws+WS_BO,
                     (const f16x2*)(ws+WS_WX2), (const f16x2*)(ws+WS_WO2), (const f16x2*)(ws+WS_WF2),
                     ws+WS_OUTK, ws+WS_D2, ws+WS_F2);
  hipLaunchKernelGGL(final_kernel, dim3(NB/256), dim3(256), 0, stream,
                     ws+WS_D2, ws+WS_F2, ws+WS_OUTK, bf, out);
}

// Round 6
// 4363.398 us; speedup vs baseline: 1.3893x; 1.3893x over previous
//
#include <hip/hip_runtime.h>
#include <hip/hip_fp16.h>

#define S 31
#define D 14
#define H 50
#define NB 16384
#define NITER 48
#define LAMR 1e-4f
#define SC 2.8853900817779268f   // 2*log2(e): folded into Wh,Wx,Wo,bh+bx,bo

// ws float-index layout
#define WS_D2   0      // 48: global sum ||F-X||^2 per iter
#define WS_F2   64     // 48: global sum ||F||^2 per iter
#define WS_WHP  128    // 50x16 fp32 Wh*SC (padded)
#define WS_BHX  928    // 64: (bh+bx)*SC fp32
#define WS_BO2  992    // 7 f16x2: bo*SC packed d-pairs (padded to 32 dwords)
#define WS_WX2  1024   // 50x8 f16x2: Wx*SC rows packed (d pairs)
#define WS_WOC  1424   // 50x7 f16x2: Wo*SC packed by column: woc[h*7+q]={Wo[2q][h],Wo[2q+1][h]} (pad 352)
#define WS_WF2  1776   // 32x9 f16x2: Wf per-s slices, stride 9 (row 31 = 0), UNSCALED
#define WS_OUTK 4096   // 48*NB floats

typedef _Float16 f16x2 __attribute__((ext_vector_type(2)));

#if defined(__has_builtin) && __has_builtin(__builtin_amdgcn_rcpf)
#define FRCP(x) __builtin_amdgcn_rcpf(x)
#else
#define FRCP(x) (1.0f/(x))
#endif

#define FDOT2(a,b,c) __builtin_amdgcn_fdot2((a),(b),(c),false)

__device__ __forceinline__ f16x2 pkrtz(float a, float b){
  auto r = __builtin_amdgcn_cvt_pkrtz(a, b);
  return __builtin_bit_cast(f16x2, r);
}
#define PKRTZ(a,b) pkrtz((a),(b))

// scaled tanh: input u = 2*log2(e)*x  ->  tanh(x) = 1 - 2/(2^u + 1)
__device__ __forceinline__ float tsc(float u){
  float e = __builtin_exp2f(u);
  return 1.f - 2.f * FRCP(e + 1.f);
}

// triangular index, i<=j, 6x6
#define AIJ(i,j) ((i)*6 - ((i)*((i)+1))/2 + (j))

__device__ __forceinline__ float half_red(float v){
  v += __shfl_xor(v, 1);
  v += __shfl_xor(v, 2);
  v += __shfl_xor(v, 4);
  v += __shfl_xor(v, 8);
  v += __shfl_xor(v, 16);
  return v;   // sum over 32-lane half
}

__global__ void prep_kernel(const float* __restrict__ Wh, const float* __restrict__ bh,
                            const float* __restrict__ Wx, const float* __restrict__ bx,
                            const float* __restrict__ Wo, const float* __restrict__ bo,
                            const float* __restrict__ Wf, float* __restrict__ ws){
  int t = threadIdx.x;                       // 1 block x 256
  for (int i=t;i<128;i+=256) ws[i]=0.f;      // zero norm accumulators
  for (int i=t;i<800;i+=256){
    int h=i>>4, d=i&15;
    ws[WS_WHP+i] = (d<D)? Wh[h*D+d]*SC : 0.f;
  }
  for (int i=t;i<64;i+=256) ws[WS_BHX+i] = (i<H)? (bh[i]+bx[i])*SC : 0.f;
  __half2* bo2 = (__half2*)(ws + WS_BO2);
  for (int i=t;i<7;i+=256) bo2[i] = __floats2half2_rn(bo[2*i]*SC, bo[2*i+1]*SC);
  __half2* wx2 = (__half2*)(ws + WS_WX2);
  for (int i=t;i<400;i+=256){
    int h=i>>3, dd=i&7, d0=2*dd, d1=2*dd+1;
    float a=(d0<D)?Wx[h*D+d0]*SC:0.f, b=(d1<D)?Wx[h*D+d1]*SC:0.f;
    wx2[i] = __floats2half2_rn(a,b);
  }
  __half2* woc = (__half2*)(ws + WS_WOC);
  for (int i=t;i<350;i+=256){
    int h=i/7, q=i-7*h;
    woc[i] = __floats2half2_rn(Wo[(2*q)*H+h]*SC, Wo[(2*q+1)*H+h]*SC);
  }
  __half2* wf2 = (__half2*)(ws + WS_WF2);
  for (int i=t;i<288;i+=256){
    int s=i/9, q=i-9*s;
    float a=(s<S && q<7)?Wf[s*D+2*q]:0.f, b=(s<S && q<7)?Wf[s*D+2*q+1]:0.f;
    wf2[i] = __floats2half2_rn(a,b);
  }
}

// f-eval from LDS weights: fvh = tanh( Wo @ tanh(hx + Wx @ xvh) + bo )
// phase2 uses packed-fp16 accumulation (tac) against column-packed Wo.
#define FEVAL() do{ \
  f16x2 tac[7]; \
  _Pragma("unroll") for (int q_=0;q_<7;++q_) tac[q_]=bo2s[q_]; \
  _Pragma("unroll") \
  for (int hh_=0; hh_<25; ++hh_){ \
    f16x2 hx2_ = hxs[hh_*256 + tid]; \
    float a0_ = (float)hx2_.x, b0_ = (float)hx2_.y; \
    _Pragma("unroll") for (int q_=0;q_<7;++q_){ \
      a0_ = FDOT2(xvh[q_], wxs[(2*hh_)*8+q_],   a0_); \
      b0_ = FDOT2(xvh[q_], wxs[(2*hh_+1)*8+q_], b0_); } \
    float th0_ = tsc(a0_), th1_ = tsc(b0_); \
    f16x2 t0_ = PKRTZ(th0_, th0_), t1_ = PKRTZ(th1_, th1_); \
    _Pragma("unroll") for (int q_=0;q_<7;++q_){ \
      tac[q_] = t0_*wocs[(2*hh_)*7+q_]   + tac[q_]; \
      tac[q_] = t1_*wocs[(2*hh_+1)*7+q_] + tac[q_]; } \
  } \
  _Pragma("unroll") for (int q_=0;q_<7;++q_) \
    fvh[q_] = PKRTZ(tsc((float)tac[q_].x), tsc((float)tac[q_].y)); \
}while(0)

// zero F (fvh) and G (xvh, aliased) on inactive lanes
#define ZERO_INACT() do{ \
  if (!act){ \
    _Pragma("unroll") for (int q_=0;q_<7;++q_){ fvh[q_]=zzv; xvh[q_]=zzv; } \
  } \
}while(0)

// push (F=fvh, G=xvh) as newest history entry (slot 5), update triangular GG
#define PUSH() do{ \
  float dnew_[5]; \
  _Pragma("unroll") for (int j_=0;j_<5;++j_){ \
    float acc_=0.f; \
    _Pragma("unroll") for (int q_=0;q_<7;++q_) acc_ = FDOT2(xvh[q_], Gh[(j_+1)*7+q_], acc_); \
    dnew_[j_] = half_red(acc_); } \
  float d2l=0.f, f2l=0.f; \
  _Pragma("unroll") for (int q_=0;q_<7;++q_){ \
    d2l = FDOT2(xvh[q_], xvh[q_], d2l); \
    f2l = FDOT2(fvh[q_], fvh[q_], f2l); } \
  d2r = half_red(d2l); f2r = half_red(f2l); \
  _Pragma("unroll") for (int j_=0;j_<5;++j_) \
    _Pragma("unroll") for (int q_=0;q_<7;++q_){ \
      Fh[j_*7+q_] = Fh[(j_+1)*7+q_]; Gh[j_*7+q_] = Gh[(j_+1)*7+q_]; } \
  _Pragma("unroll") for (int q_=0;q_<7;++q_){ Fh[35+q_]=fvh[q_]; Gh[35+q_]=xvh[q_]; } \
  _Pragma("unroll") for (int i_=0;i_<5;++i_) \
    _Pragma("unroll") for (int j_=i_;j_<5;++j_) GG[AIJ(i_,j_)] = GG[AIJ(i_+1,j_+1)]; \
  _Pragma("unroll") for (int j_=0;j_<5;++j_) GG[AIJ(j_,5)] = dnew_[j_]; \
  GG[AIJ(5,5)] = d2r; \
}while(0)

__global__ __launch_bounds__(256)
void solver_kernel(const float* __restrict__ x,
                   const float* __restrict__ whp, const float* __restrict__ bhx,
                   const f16x2* __restrict__ bo2g,
                   const f16x2* __restrict__ wx2g, const f16x2* __restrict__ wocg,
                   const f16x2* __restrict__ wf2g,
                   float* __restrict__ outk, float* __restrict__ d2p, float* __restrict__ f2p){
  const int tid  = threadIdx.x;
  const int lane = tid & 63;
  const int s    = tid & 31;
  const int elem = blockIdx.x*8 + (tid>>5);
  const bool act = (s < S);

  __shared__ f16x2 hxs[25*256];   // [hh][tid]: lane-consecutive -> 2-way (free)
  __shared__ f16x2 wxs[400];      // Wx*SC [50][8]  (uniform reads -> broadcast)
  __shared__ f16x2 wocs[352];     // Wo*SC cols [50][7]
  __shared__ f16x2 wfs[288];      // Wf [32][9] stride-9 (coprime w/ 32 banks)
  __shared__ f16x2 bo2s[8];       // bo*SC d-pairs

  // stage weights to LDS (grid-stride: cover ALL entries with 256 threads)
  for (int i=tid;i<400;i+=256) wxs[i]=wx2g[i];
  for (int i=tid;i<350;i+=256) wocs[i]=wocg[i];
  for (int i=tid;i<288;i+=256) wfs[i]=wf2g[i];
  if (tid<7)   bo2s[tid]=bo2g[tid];

  { // prologue: hx[h] = SC*(x_s . Wh_h + bh_h + bx_h), fp32 math, fp16 store
    float xd[D];
#pragma unroll
    for (int d=0; d<D; ++d) xd[d]=0.f;
    if (act){
      const float* xr = x + ((size_t)elem*S + s)*D;
#pragma unroll
      for (int d=0; d<D; ++d) xd[d]=xr[d];
    }
#pragma unroll 1
    for (int hh=0; hh<25; ++hh){
      float a0 = bhx[2*hh], a1 = 0.f, b0 = bhx[2*hh+1], b1 = 0.f;
#pragma unroll
      for (int d=0; d<D; d+=2){
        a0 += xd[d]*whp[(2*hh)*16+d];   a1 += xd[d+1]*whp[(2*hh)*16+d+1];
        b0 += xd[d]*whp[(2*hh+1)*16+d]; b1 += xd[d+1]*whp[(2*hh+1)*16+d+1];
      }
      hxs[hh*256+tid] = PKRTZ(a0+a1, b0+b1);
    }
  }
  __syncthreads();

  const f16x2 zzv = {(_Float16)0.f, (_Float16)0.f};

  f16x2 Fh[42], Gh[42], xvh[7], fvh[7];
  float GG[21];
  float d2r, f2r;
#pragma unroll
  for (int i=0;i<42;++i){ Fh[i]=zzv; Gh[i]=zzv; }
#pragma unroll
  for (int i=0;i<21;++i) GG[i]=0.f;

  // init entry 0: X0=0, F0=f(0), G0=F0
#pragma unroll
  for (int q=0;q<7;++q) xvh[q]=zzv;
  FEVAL();
#pragma unroll
  for (int q=0;q<7;++q) xvh[q]=fvh[q]-xvh[q];
  ZERO_INACT();
  PUSH();
  // init entry 1: X1=F0, F1=f(F0)
#pragma unroll
  for (int q=0;q<7;++q) xvh[q]=Fh[35+q];
  FEVAL();
#pragma unroll
  for (int q=0;q<7;++q) xvh[q]=fvh[q]-xvh[q];
  ZERO_INACT();
  PUSH();

#pragma unroll 1
  for (int kk=2; kk<50; ++kk){
    float A_[21], yv[6];
    if (kk >= 6){
#pragma unroll
      for (int i=0;i<6;++i)
#pragma unroll
        for (int j=i;j<6;++j) A_[AIJ(i,j)] = GG[AIJ(i,j)] + ((i==j)?LAMR:0.f);
    } else {
      int lo = 6-kk;
#pragma unroll
      for (int i=0;i<6;++i)
#pragma unroll
        for (int j=i;j<6;++j){
          float v = GG[AIJ(i,j)] + ((i==j)?LAMR:0.f);
          A_[AIJ(i,j)] = (i>=lo)? v : ((i==j)?1e30f:0.f);
        }
    }
#pragma unroll
    for (int i=0;i<6;++i) yv[i]=1.f;
    // symmetric GE (no pivoting; SPD + big-diag pads); diag holds inverse
#pragma unroll
    for (int p=0;p<6;++p){
      float inv = FRCP(A_[AIJ(p,p)]);
      A_[AIJ(p,p)] = inv;
#pragma unroll
      for (int i=p+1;i<6;++i){
        float m = A_[AIJ(p,i)]*inv;
#pragma unroll
        for (int j=i;j<6;++j) A_[AIJ(i,j)] -= m*A_[AIJ(p,j)];
        yv[i] -= m*yv[p];
      }
    }
#pragma unroll
    for (int p=5;p>=0;--p){
      float acc=yv[p];
#pragma unroll
      for (int j=p+1;j<6;++j) acc -= A_[AIJ(p,j)]*yv[j];
      yv[p]=acc*A_[AIJ(p,p)];
    }
    float isum = FRCP(yv[0]+yv[1]+yv[2]+yv[3]+yv[4]+yv[5]);
    // Xk = sum_j alpha_j F_j  (fp16 packed)
#pragma unroll
    for (int q=0;q<7;++q) xvh[q]=zzv;
#pragma unroll
    for (int j=0;j<6;++j){
      _Float16 ah = (_Float16)(yv[j]*isum);
      f16x2 a2 = {ah, ah};
#pragma unroll
      for (int q=0;q<7;++q) xvh[q] += a2*Fh[j*7+q];
    }
    FEVAL();
#pragma unroll
    for (int q=0;q<7;++q) xvh[q]=fvh[q]-xvh[q];   // xvh now holds G
    ZERO_INACT();
    PUSH();
    // projection through Wf for this iterate
    float po=0.f;
    const f16x2* wfr = wfs + s*9;
#pragma unroll
    for (int q=0;q<7;++q) po = FDOT2(fvh[q], wfr[q], po);
    po = half_red(po);
    float d2w = d2r + __shfl_xor(d2r, 32);
    float f2w = f2r + __shfl_xor(f2r, 32);
    if (lane==0){ atomicAdd(&d2p[kk-2], d2w); atomicAdd(&f2p[kk-2], f2w); }
    if (s==0) outk[(size_t)(kk-2)*NB + elem] = po;
  }
}

__global__ void final_kernel(const float* __restrict__ d2p, const float* __restrict__ f2p,
                             const float* __restrict__ outk, const float* __restrict__ bf,
                             float* __restrict__ out){
  int b = blockIdx.x*blockDim.x + threadIdx.x;
  float best = 1e8f; int kst = 0;
  for (int k=0;k<NITER;++k){
    float rel = sqrtf(d2p[k]) / (1e-5f + sqrtf(f2p[k]));
    if (rel < best){ best = rel; kst = k; }
  }
  out[b] = outk[(size_t)kst*NB + b] + bf[0];
}

extern "C" void kernel_launch(void* const* d_in, const int* in_sizes, int n_in,
                              void* d_out, int out_size, void* d_ws, size_t ws_size,
                              hipStream_t stream){
  const float* x  = (const float*)d_in[0];
  const float* Wh = (const float*)d_in[1];
  const float* bh = (const float*)d_in[2];
  const float* Wx = (const float*)d_in[3];
  const float* bx = (const float*)d_in[4];
  const float* Wo = (const float*)d_in[5];
  const float* bo = (const float*)d_in[6];
  const float* Wf = (const float*)d_in[7];
  const float* bf = (const float*)d_in[8];
  float* ws  = (float*)d_ws;
  float* out = (float*)d_out;

  hipLaunchKernelGGL(prep_kernel, dim3(1), dim3(256), 0, stream, Wh,bh,Wx,bx,Wo,bo,Wf,ws);
  hipLaunchKernelGGL(solver_kernel, dim3(NB/8), dim3(256), 0, stream,
                     x, ws+WS_WHP, ws+WS_BHX,
                     (const f16x2*)(ws+WS_BO2),
                     (const f16x2*)(ws+WS_WX2), (const f16x2*)(ws+WS_WOC), (const f16x2*)(ws+WS_WF2),
                     ws+WS_OUTK, ws+WS_D2, ws+WS_F2);
  hipLaunchKernelGGL(final_kernel, dim3(NB/256), dim3(256), 0, stream,
                     ws+WS_D2, ws+WS_F2, ws+WS_OUTK, bf, out);
}

// Round 7
// 4176.531 us; speedup vs baseline: 1.4515x; 1.0447x over previous
//
#include <hip/hip_runtime.h>
#include <hip/hip_fp16.h>

#define S 31
#define D 14
#define H 50
#define NB 16384
#define NITER 48
#define LAMR 1e-4f
#define SC 2.8853900817779268f   // 2*log2(e): folded into Wh,Wx,Wo,bh+bx,bo

// ws float-index layout
#define WS_D2   0      // 48: global sum ||F-X||^2 per iter
#define WS_F2   64     // 48: global sum ||F||^2 per iter
#define WS_WHP  128    // 50x16 fp32 Wh*SC (padded)
#define WS_BHX  928    // 64: (bh+bx)*SC fp32
#define WS_BO2  992    // 7 f16x2: bo*SC packed d-pairs
#define WS_WX2  1024   // 50x8 f16x2: Wx*SC rows packed (d pairs)
#define WS_WOC  1424   // 50x7 f16x2: Wo*SC column-packed (pad 352)
#define WS_WF2  1776   // 32x9 f16x2: Wf per-s slices, stride 9
#define WS_OUTK 4096   // 48*NB floats

typedef _Float16 f16x2 __attribute__((ext_vector_type(2)));

#if defined(__has_builtin) && __has_builtin(__builtin_amdgcn_rcpf)
#define FRCP(x) __builtin_amdgcn_rcpf(x)
#else
#define FRCP(x) (1.0f/(x))
#endif

#define FDOT2(a,b,c) __builtin_amdgcn_fdot2((a),(b),(c),false)

__device__ __forceinline__ f16x2 pkrtz(float a, float b){
  auto r = __builtin_amdgcn_cvt_pkrtz(a, b);
  return __builtin_bit_cast(f16x2, r);
}
#define PKRTZ(a,b) pkrtz((a),(b))

// scaled tanh: input u = 2*log2(e)*x  ->  tanh(x) = 1 - 2/(2^u + 1)
__device__ __forceinline__ float tsc(float u){
  float e = __builtin_exp2f(u);
  return 1.f - 2.f * FRCP(e + 1.f);
}

// triangular index, i<=j, 6x6
#define AIJ(i,j) ((i)*6 - ((i)*((i)+1))/2 + (j))

__device__ __forceinline__ float half_red(float v){
  v += __shfl_xor(v, 1);
  v += __shfl_xor(v, 2);
  v += __shfl_xor(v, 4);
  v += __shfl_xor(v, 8);
  v += __shfl_xor(v, 16);
  return v;   // sum over 32-lane half
}

__global__ void prep_kernel(const float* __restrict__ Wh, const float* __restrict__ bh,
                            const float* __restrict__ Wx, const float* __restrict__ bx,
                            const float* __restrict__ Wo, const float* __restrict__ bo,
                            const float* __restrict__ Wf, float* __restrict__ ws){
  int t = threadIdx.x;                       // 1 block x 256
  for (int i=t;i<128;i+=256) ws[i]=0.f;      // zero norm accumulators
  for (int i=t;i<800;i+=256){
    int h=i>>4, d=i&15;
    ws[WS_WHP+i] = (d<D)? Wh[h*D+d]*SC : 0.f;
  }
  for (int i=t;i<64;i+=256) ws[WS_BHX+i] = (i<H)? (bh[i]+bx[i])*SC : 0.f;
  __half2* bo2 = (__half2*)(ws + WS_BO2);
  for (int i=t;i<7;i+=256) bo2[i] = __floats2half2_rn(bo[2*i]*SC, bo[2*i+1]*SC);
  __half2* wx2 = (__half2*)(ws + WS_WX2);
  for (int i=t;i<400;i+=256){
    int h=i>>3, dd=i&7, d0=2*dd, d1=2*dd+1;
    float a=(d0<D)?Wx[h*D+d0]*SC:0.f, b=(d1<D)?Wx[h*D+d1]*SC:0.f;
    wx2[i] = __floats2half2_rn(a,b);
  }
  __half2* woc = (__half2*)(ws + WS_WOC);
  for (int i=t;i<350;i+=256){
    int h=i/7, q=i-7*h;
    woc[i] = __floats2half2_rn(Wo[(2*q)*H+h]*SC, Wo[(2*q+1)*H+h]*SC);
  }
  __half2* wf2 = (__half2*)(ws + WS_WF2);
  for (int i=t;i<288;i+=256){
    int s=i/9, q=i-9*s;
    float a=(s<S && q<7)?Wf[s*D+2*q]:0.f, b=(s<S && q<7)?Wf[s*D+2*q+1]:0.f;
    wf2[i] = __floats2half2_rn(a,b);
  }
}

// f-eval from LDS weights: fvh = tanh( Wo @ tanh(hx + Wx @ xvh) + bo )
#define FEVAL() do{ \
  f16x2 tac[7]; \
  _Pragma("unroll") for (int q_=0;q_<7;++q_) tac[q_]=bo2s[q_]; \
  _Pragma("unroll") \
  for (int hh_=0; hh_<25; ++hh_){ \
    f16x2 hx2_ = hxs[hh_*256 + tid]; \
    float a0_ = (float)hx2_.x, b0_ = (float)hx2_.y; \
    _Pragma("unroll") for (int q_=0;q_<7;++q_){ \
      a0_ = FDOT2(xvh[q_], wxs[(2*hh_)*8+q_],   a0_); \
      b0_ = FDOT2(xvh[q_], wxs[(2*hh_+1)*8+q_], b0_); } \
    float th0_ = tsc(a0_), th1_ = tsc(b0_); \
    f16x2 t0_ = PKRTZ(th0_, th0_), t1_ = PKRTZ(th1_, th1_); \
    _Pragma("unroll") for (int q_=0;q_<7;++q_){ \
      tac[q_] = t0_*wocs[(2*hh_)*7+q_]   + tac[q_]; \
      tac[q_] = t1_*wocs[(2*hh_+1)*7+q_] + tac[q_]; } \
  } \
  _Pragma("unroll") for (int q_=0;q_<7;++q_) \
    fvh[q_] = PKRTZ(tsc((float)tac[q_].x), tsc((float)tac[q_].y)); \
}while(0)

__global__ __launch_bounds__(256)
void solver_kernel(const float* __restrict__ x,
                   const float* __restrict__ whp, const float* __restrict__ bhx,
                   const f16x2* __restrict__ bo2g,
                   const f16x2* __restrict__ wx2g, const f16x2* __restrict__ wocg,
                   const f16x2* __restrict__ wf2g,
                   float* __restrict__ outk, float* __restrict__ d2p, float* __restrict__ f2p){
  const int tid  = threadIdx.x;
  const int lane = tid & 63;
  const int s    = tid & 31;
  const int elem = blockIdx.x*8 + (tid>>5);
  const bool act = (s < S);

  __shared__ f16x2 hxs[25*256];   // [hh][tid]: lane-consecutive -> 2-way (free)
  __shared__ f16x2 wxs[400];      // Wx*SC [50][8]  (uniform reads -> broadcast)
  __shared__ f16x2 wocs[352];     // Wo*SC cols [50][7]
  __shared__ f16x2 wfs[288];      // Wf [32][9] stride-9
  __shared__ f16x2 bo2s[8];       // bo*SC d-pairs
  __shared__ float ggl[8*24];     // per-element triangular GG (21 used)

  // stage weights to LDS
  for (int i=tid;i<400;i+=256) wxs[i]=wx2g[i];
  for (int i=tid;i<350;i+=256) wocs[i]=wocg[i];
  for (int i=tid;i<288;i+=256) wfs[i]=wf2g[i];
  if (tid<8)   bo2s[tid] = (tid<7)? bo2g[tid] : f16x2{(_Float16)0.f,(_Float16)0.f};
  for (int i=tid;i<192;i+=256) ggl[i]=0.f;

  { // prologue: hx[h] = SC*(x_s . Wh_h + bh_h + bx_h), fp32 math, fp16 store
    float xd[D];
#pragma unroll
    for (int d=0; d<D; ++d) xd[d]=0.f;
    if (act){
      const float* xr = x + ((size_t)elem*S + s)*D;
#pragma unroll
      for (int d=0; d<D; ++d) xd[d]=xr[d];
    }
#pragma unroll 1
    for (int hh=0; hh<25; ++hh){
      float a0 = bhx[2*hh], a1 = 0.f, b0 = bhx[2*hh+1], b1 = 0.f;
#pragma unroll
      for (int d=0; d<D; d+=2){
        a0 += xd[d]*whp[(2*hh)*16+d];   a1 += xd[d+1]*whp[(2*hh)*16+d+1];
        b0 += xd[d]*whp[(2*hh+1)*16+d]; b1 += xd[d+1]*whp[(2*hh+1)*16+d+1];
      }
      hxs[hh*256+tid] = PKRTZ(a0+a1, b0+b1);
    }
  }
  __syncthreads();

  const f16x2 zzv = {(_Float16)0.f, (_Float16)0.f};
  float* gge = ggl + (tid>>5)*24;
  const bool writer = (s == 0);

  f16x2 Fh[42], Gh[42], xvh[7], fvh[7];
#pragma unroll
  for (int i=0;i<42;++i){ Fh[i]=zzv; Gh[i]=zzv; }

  // folded loop: kk=0 -> (X0=0,F0), kk=1 -> (X1=F0,F1), kk>=2 -> Anderson
#pragma unroll 1
  for (int kk=0; kk<50; ++kk){
    if (kk >= 2){
      float A_[21], yv[6];
      if (kk >= 6){
#pragma unroll
        for (int i=0;i<6;++i)
#pragma unroll
          for (int j=i;j<6;++j) A_[AIJ(i,j)] = gge[AIJ(i,j)] + ((i==j)?LAMR:0.f);
      } else {
        int lo = 6-kk;
#pragma unroll
        for (int i=0;i<6;++i)
#pragma unroll
          for (int j=i;j<6;++j){
            float v = gge[AIJ(i,j)] + ((i==j)?LAMR:0.f);
            A_[AIJ(i,j)] = (i>=lo)? v : ((i==j)?1e30f:0.f);
          }
      }
#pragma unroll
      for (int i=0;i<6;++i) yv[i]=1.f;
      // symmetric GE (no pivoting; SPD + big-diag pads); diag holds inverse
#pragma unroll
      for (int p=0;p<6;++p){
        float inv = FRCP(A_[AIJ(p,p)]);
        A_[AIJ(p,p)] = inv;
#pragma unroll
        for (int i=p+1;i<6;++i){
          float m = A_[AIJ(p,i)]*inv;
#pragma unroll
          for (int j=i;j<6;++j) A_[AIJ(i,j)] -= m*A_[AIJ(p,j)];
          yv[i] -= m*yv[p];
        }
      }
#pragma unroll
      for (int p=5;p>=0;--p){
        float acc=yv[p];
#pragma unroll
        for (int j=p+1;j<6;++j) acc -= A_[AIJ(p,j)]*yv[j];
        yv[p]=acc*A_[AIJ(p,p)];
      }
      float isum = FRCP(yv[0]+yv[1]+yv[2]+yv[3]+yv[4]+yv[5]);
      // Xk = sum_j alpha_j F_j  (fp16 packed)
#pragma unroll
      for (int q=0;q<7;++q) xvh[q]=zzv;
#pragma unroll
      for (int j=0;j<6;++j){
        _Float16 ah = (_Float16)(yv[j]*isum);
        f16x2 a2 = {ah, ah};
#pragma unroll
        for (int q=0;q<7;++q) xvh[q] += a2*Fh[j*7+q];
      }
    } else if (kk == 1){
#pragma unroll
      for (int q=0;q<7;++q) xvh[q]=Fh[35+q];   // X1 = F0 (slot5 = newest)
    } else {
#pragma unroll
      for (int q=0;q<7;++q) xvh[q]=zzv;        // X0 = 0
    }

    FEVAL();
#pragma unroll
    for (int q=0;q<7;++q) xvh[q]=fvh[q]-xvh[q];   // xvh now holds G
    if (!act){
#pragma unroll
      for (int q=0;q<7;++q){ fvh[q]=zzv; xvh[q]=zzv; }
    }

    // PUSH: dots vs old slots 1..5 (pre-shift), norms, reg shift, LDS GG shift+update
    float dnew_[5], d2r, f2r;
#pragma unroll
    for (int j=0;j<5;++j){
      float acc=0.f;
#pragma unroll
      for (int q=0;q<7;++q) acc = FDOT2(xvh[q], Gh[(j+1)*7+q], acc);
      dnew_[j] = half_red(acc);
    }
    {
      float d2l=0.f, f2l=0.f;
#pragma unroll
      for (int q=0;q<7;++q){
        d2l = FDOT2(xvh[q], xvh[q], d2l);
        f2l = FDOT2(fvh[q], fvh[q], f2l);
      }
      d2r = half_red(d2l); f2r = half_red(f2l);
    }
#pragma unroll
    for (int j=0;j<5;++j)
#pragma unroll
      for (int q=0;q<7;++q){
        Fh[j*7+q] = Fh[(j+1)*7+q]; Gh[j*7+q] = Gh[(j+1)*7+q];
      }
#pragma unroll
    for (int q=0;q<7;++q){ Fh[35+q]=fvh[q]; Gh[35+q]=xvh[q]; }
    if (writer){
      float t[21];
#pragma unroll
      for (int i=0;i<5;++i)
#pragma unroll
        for (int j=i;j<5;++j) t[AIJ(i,j)] = gge[AIJ(i+1,j+1)];
#pragma unroll
      for (int i=0;i<5;++i)
#pragma unroll
        for (int j=i;j<5;++j) gge[AIJ(i,j)] = t[AIJ(i,j)];
#pragma unroll
      for (int j=0;j<5;++j) gge[AIJ(j,5)] = dnew_[j];
      gge[AIJ(5,5)] = d2r;
    }

    if (kk >= 2){
      // projection through Wf for this iterate
      float po=0.f;
      const f16x2* wfr = wfs + s*9;
#pragma unroll
      for (int q=0;q<7;++q) po = FDOT2(fvh[q], wfr[q], po);
      po = half_red(po);
      float d2w = d2r + __shfl_xor(d2r, 32);
      float f2w = f2r + __shfl_xor(f2r, 32);
      if (lane==0){ atomicAdd(&d2p[kk-2], d2w); atomicAdd(&f2p[kk-2], f2w); }
      if (s==0) outk[(size_t)(kk-2)*NB + elem] = po;
    }
  }
}

__global__ void final_kernel(const float* __restrict__ d2p, const float* __restrict__ f2p,
                             const float* __restrict__ outk, const float* __restrict__ bf,
                             float* __restrict__ out){
  int b = blockIdx.x*blockDim.x + threadIdx.x;
  float best = 1e8f; int kst = 0;
  for (int k=0;k<NITER;++k){
    float rel = sqrtf(d2p[k]) / (1e-5f + sqrtf(f2p[k]));
    if (rel < best){ best = rel; kst = k; }
  }
  out[b] = outk[(size_t)kst*NB + b] + bf[0];
}

extern "C" void kernel_launch(void* const* d_in, const int* in_sizes, int n_in,
                              void* d_out, int out_size, void* d_ws, size_t ws_size,
                              hipStream_t stream){
  const float* x  = (const float*)d_in[0];
  const float* Wh = (const float*)d_in[1];
  const float* bh = (const float*)d_in[2];
  const float* Wx = (const float*)d_in[3];
  const float* bx = (const float*)d_in[4];
  const float* Wo = (const float*)d_in[5];
  const float* bo = (const float*)d_in[6];
  const float* Wf = (const float*)d_in[7];
  const float* bf = (const float*)d_in[8];
  float* ws  = (float*)d_ws;
  float* out = (float*)d_out;

  hipLaunchKernelGGL(prep_kernel, dim3(1), dim3(256), 0, stream, Wh,bh,Wx,bx,Wo,bo,Wf,ws);
  hipLaunchKernelGGL(solver_kernel, dim3(NB/8), dim3(256), 0, stream,
                     x, ws+WS_WHP, ws+WS_BHX,
                     (const f16x2*)(ws+WS_BO2),
                     (const f16x2*)(ws+WS_WX2), (const f16x2*)(ws+WS_WOC), (const f16x2*)(ws+WS_WF2),
                     ws+WS_OUTK, ws+WS_D2, ws+WS_F2);
  hipLaunchKernelGGL(final_kernel, dim3(NB/256), dim3(256), 0, stream,
                     ws+WS_D2, ws+WS_F2, ws+WS_OUTK, bf, out);
}